// Round 9
// baseline (282.517 us; speedup 1.0000x reference)
//
#include <hip/hip_runtime.h>

typedef __attribute__((ext_vector_type(4))) float f32x4;
typedef __attribute__((ext_vector_type(8))) short s16x8;
typedef __attribute__((ext_vector_type(4))) unsigned short u16x4;

struct F2 { float c, s; };

__device__ __forceinline__ unsigned short f2b(float f) {
  unsigned u = __builtin_bit_cast(unsigned, f);
  u += 0x7FFFu + ((u >> 16) & 1u);
  return (unsigned short)(u >> 16);
}
__device__ __forceinline__ void gll16(const void* g, void* l) {
  __builtin_amdgcn_global_load_lds(
      (const __attribute__((address_space(1))) unsigned int*)g,
      (__attribute__((address_space(3))) unsigned int*)l, 16, 0, 0);
}
__device__ __forceinline__ f32x4 mfma16(s16x8 a, s16x8 b, f32x4 c) {
  return __builtin_amdgcn_mfma_f32_16x16x32_bf16(a, b, c, 0, 0, 0);
}

// ---------------- kernel 0: fused prep — input f32->bf16 cvt + RoPE sin/cos table -------
__global__ void k_prep(const float* __restrict__ Xq, const float* __restrict__ Xkv,
                       unsigned short* __restrict__ Xqb, unsigned short* __restrict__ Xkvb,
                       F2* __restrict__ tab) {
  int b = blockIdx.x;
  if (b < 4096) {
    const float* src = (b < 2048) ? Xq : Xkv;
    unsigned short* dst = (b < 2048) ? Xqb : Xkvb;
    int i = (b & 2047) * 256 + threadIdx.x;
    for (; i < 4194304; i += 2048 * 256) {
      f32x4 v = ((const f32x4*)src)[i];
      u16x4 o;
      o.x = f2b(v.x); o.y = f2b(v.y); o.z = f2b(v.z); o.w = f2b(v.w);
      ((u16x4*)dst)[i] = o;
    }
  } else {
    int idx = (b - 4096) * 256 + threadIdx.x;   // 65536 entries
    int pos = idx >> 4, fi = idx & 15;
    double inv = exp((double)fi * (-9.210340371976184 / 16.0));  // 10000^(-fi/16)
    double a = (double)pos * inv;
    F2 r; r.c = (float)cos(a); r.s = (float)sin(a);
    tab[idx] = r;
  }
}

// ---------------- kernel 2: transpose weights f32 [K][N] -> bf16 [N][K] -----------------
__global__ void k_transpose(const float* __restrict__ wq,
                            const float* __restrict__ wk,
                            const float* __restrict__ wv,
                            const float* __restrict__ wo,
                            unsigned short* __restrict__ wtqkv,
                            unsigned short* __restrict__ wto) {
  __shared__ unsigned short tile[32][33];
  int z = blockIdx.z;
  const float* src = (z == 0) ? wq : (z == 1) ? wk : (z == 2) ? wv : wo;
  unsigned short* dst = (z < 3) ? (wtqkv + (size_t)z * 1048576) : wto;
  int bx = blockIdx.x * 32, by = blockIdx.y * 32;
  tile[threadIdx.y][threadIdx.x] = f2b(src[(size_t)(by + threadIdx.y) * 1024 + bx + threadIdx.x]);
  __syncthreads();
  dst[(size_t)(bx + threadIdx.y) * 1024 + by + threadIdx.x] = tile[threadIdx.x][threadIdx.y];
}

// ---------------- 8-phase 256x256 GEMM core, 16 waves (4 waves/SIMD) --------------------
// Same data/sync schedule as round-5, re-gridded to 1024 threads: wave (wm,wn) owns a
// 64x64 output block, acc[4][4] (64 VGPR). Staging: one gll16 per thread per half-tile.
// vmcnt ledger (1 load per SA/SB call): steady in-flight at ph4 = 6 {A0A1(t+1) prev,
// B0B1(t+1) ph1/2, A0A1(t+2) ph3/4}; vmcnt(2) drains through B1(t+1) => tile t+1 resident.
__device__ __forceinline__ void gemm_core(
    const unsigned short* __restrict__ Ag, const unsigned short* __restrict__ Bg,
    int m0, int n0, unsigned short* Sh, f32x4 (&acc)[4][4]) {
  const int tid = threadIdx.x, wid = tid >> 6, lane = tid & 63;
  const int fr = lane & 15, fg = lane >> 4, f7 = fr & 7;
  const int wm = wid >> 2, wn = wid & 3;
  const int g0 = (fg ^ f7) * 8, g1 = ((4 + fg) ^ f7) * 8;
  const int scp = lane & 7;
  const int srow = wid * 8 + (lane >> 3);          // staging row within 128-row half

  auto SA = [&](int T, int ah) {
    unsigned short* dstb = Sh + (T & 1) * 32768;
    int row = ah * 128 + srow;
    gll16(Ag + (size_t)(m0 + row) * 1024 + T * 64 + (scp ^ (row & 7)) * 8,
          dstb + (ah * 128 + wid * 8) * 64);       // wave-uniform LDS base
  };
  auto SB = [&](int T, int bh) {
    unsigned short* dstb = Sh + (T & 1) * 32768 + 16384;
    int row = bh * 128 + srow;
    gll16(Bg + (size_t)(n0 + row) * 1024 + T * 64 + (scp ^ (row & 7)) * 8,
          dstb + (bh * 128 + wid * 8) * 64);
  };

  SA(0, 0); SA(0, 1); SB(0, 0); SB(0, 1); SA(1, 0); SA(1, 1);
  asm volatile("s_waitcnt vmcnt(2)" ::: "memory");   // tile0 resident, A(1) in flight
  __builtin_amdgcn_sched_barrier(0);
  __builtin_amdgcn_s_barrier();

  for (int t = 0; t < 16; ++t) {
    const unsigned short* bufA = Sh + (t & 1) * 32768;
    const unsigned short* bufB = bufA + 16384;
    s16x8 a0[2][2], a1[2][2], b0[2][2], b1[2][2];
    // ph1: read a0(mf0,1)+b0(nf0,1); stage B0(t+1); Q1 = a0 x b0
#pragma unroll
    for (int mf = 0; mf < 2; ++mf) {
      const unsigned short* r = &bufA[(wm * 64 + mf * 16 + fr) * 64];
      a0[mf][0] = *(const s16x8*)&r[g0];
      a0[mf][1] = *(const s16x8*)&r[g1];
    }
#pragma unroll
    for (int nf = 0; nf < 2; ++nf) {
      const unsigned short* r = &bufB[(wn * 64 + nf * 16 + fr) * 64];
      b0[nf][0] = *(const s16x8*)&r[g0];
      b0[nf][1] = *(const s16x8*)&r[g1];
    }
    if (t + 1 < 16) SB(t + 1, 0);
    __builtin_amdgcn_s_barrier();
    asm volatile("s_waitcnt lgkmcnt(0)" ::: "memory");
    __builtin_amdgcn_sched_barrier(0);
    __builtin_amdgcn_s_setprio(1);
#pragma unroll
    for (int mf = 0; mf < 2; ++mf)
#pragma unroll
      for (int nf = 0; nf < 2; ++nf) {
        acc[mf][nf] = mfma16(a0[mf][0], b0[nf][0], acc[mf][nf]);
        acc[mf][nf] = mfma16(a0[mf][1], b0[nf][1], acc[mf][nf]);
      }
    __builtin_amdgcn_s_setprio(0);
    __builtin_amdgcn_s_barrier();
    // ph2: read a1(mf2,3); stage B1(t+1); Q2 = a1 x b0
#pragma unroll
    for (int mf = 0; mf < 2; ++mf) {
      const unsigned short* r = &bufA[(wm * 64 + 32 + mf * 16 + fr) * 64];
      a1[mf][0] = *(const s16x8*)&r[g0];
      a1[mf][1] = *(const s16x8*)&r[g1];
    }
    if (t + 1 < 16) SB(t + 1, 1);
    __builtin_amdgcn_s_barrier();
    asm volatile("s_waitcnt lgkmcnt(0)" ::: "memory");
    __builtin_amdgcn_sched_barrier(0);
    __builtin_amdgcn_s_setprio(1);
#pragma unroll
    for (int mf = 0; mf < 2; ++mf)
#pragma unroll
      for (int nf = 0; nf < 2; ++nf) {
        acc[2 + mf][nf] = mfma16(a1[mf][0], b0[nf][0], acc[2 + mf][nf]);
        acc[2 + mf][nf] = mfma16(a1[mf][1], b0[nf][1], acc[2 + mf][nf]);
      }
    __builtin_amdgcn_s_setprio(0);
    __builtin_amdgcn_s_barrier();                    // all A(t) reads done
    // ph3: read b1(nf2,3); stage A0(t+2) into this buffer; Q3 = a1 x b1
#pragma unroll
    for (int nf = 0; nf < 2; ++nf) {
      const unsigned short* r = &bufB[(wn * 64 + 32 + nf * 16 + fr) * 64];
      b1[nf][0] = *(const s16x8*)&r[g0];
      b1[nf][1] = *(const s16x8*)&r[g1];
    }
    if (t + 2 < 16) SA(t + 2, 0);
    __builtin_amdgcn_s_barrier();
    asm volatile("s_waitcnt lgkmcnt(0)" ::: "memory");
    __builtin_amdgcn_sched_barrier(0);
    __builtin_amdgcn_s_setprio(1);
#pragma unroll
    for (int mf = 0; mf < 2; ++mf)
#pragma unroll
      for (int nf = 0; nf < 2; ++nf) {
        acc[2 + mf][2 + nf] = mfma16(a1[mf][0], b1[nf][0], acc[2 + mf][2 + nf]);
        acc[2 + mf][2 + nf] = mfma16(a1[mf][1], b1[nf][1], acc[2 + mf][2 + nf]);
      }
    __builtin_amdgcn_s_setprio(0);
    __builtin_amdgcn_s_barrier();
    // ph4: stage A1(t+2); counted vmcnt; Q4 = a0 x b1
    if (t + 2 < 16) SA(t + 2, 1);
    if (t < 14) asm volatile("s_waitcnt vmcnt(2)" ::: "memory");  // tile t+1 resident
    else        asm volatile("s_waitcnt vmcnt(0)" ::: "memory");
    __builtin_amdgcn_sched_barrier(0);
    __builtin_amdgcn_s_barrier();
    __builtin_amdgcn_s_setprio(1);
#pragma unroll
    for (int mf = 0; mf < 2; ++mf)
#pragma unroll
      for (int nf = 0; nf < 2; ++nf) {
        acc[mf][2 + nf] = mfma16(a0[mf][0], b1[nf][0], acc[mf][2 + nf]);
        acc[mf][2 + nf] = mfma16(a0[mf][1], b1[nf][1], acc[mf][2 + nf]);
      }
    __builtin_amdgcn_s_setprio(0);
    __builtin_amdgcn_s_barrier();
  }
}

// ---------------- kernel 3: fused QKV GEMM + bias + RoPE + q-scale ----------------------
__global__ __launch_bounds__(1024, 1) void k_qkv(
    const unsigned short* __restrict__ Xq,
    const unsigned short* __restrict__ Xkv,
    const unsigned short* __restrict__ WT,
    const float* __restrict__ bq,
    const float* __restrict__ bk,
    const float* __restrict__ bv,
    const F2* __restrict__ tab,
    unsigned short* __restrict__ qbuf,
    unsigned short* __restrict__ kbuf,
    unsigned short* __restrict__ vbuf) {
  __shared__ __align__(16) unsigned short S[65536];   // 128 KB
  int bid = blockIdx.x;                        // 768 = 64 mt x 12 nt
  int swz = (bid & 7) * 96 + (bid >> 3);       // XCD swizzle, bijective
  int mt = swz / 12, nt = swz % 12;
  int m0 = mt * 256, n0 = nt * 256;
  int which = n0 >> 10;                        // 0=q 1=k 2=v
  const unsigned short* X = (which == 0) ? Xq : Xkv;
  const float* bias = (which == 0) ? bq : (which == 1) ? bk : bv;
  unsigned short* dst = (which == 0) ? qbuf : (which == 1) ? kbuf : vbuf;
  int n0l = n0 & 1023;
  int tid = threadIdx.x, wid = tid >> 6, lane = tid & 63;
  int fr = lane & 15, fg = lane >> 4;
  int wm = wid >> 2, wn = wid & 3;

  f32x4 acc[4][4] = {};
  gemm_core(X, WT, m0, n0, S, acc);
  // core ends with s_barrier: LDS reusable.

  // epilogue: bias + RoPE + scale, bounce via per-wave LDS (8 KB), coalesced 16B stores.
  // wave covers one full head (64 cols = head hh), rows m0+wm*64..+63.
  unsigned short* W = S + wid * 4096;          // 64 rows x 64 cols, chunk-swizzled
  int hh = (n0l + wn * 64) >> 6;
  int bn = m0 >> 8;
#pragma unroll
  for (int nf = 0; nf < 4; ++nf) {
    int d = nf * 16 + fr;                      // 0..63 within head
    int col = n0l + wn * 64 + d;
    float bz = bias[col];
    bool rope = (which < 2) && (nf < 2);       // d<32 <=> nf<2, wave-uniform
#pragma unroll
    for (int mf = 0; mf < 4; ++mf) {
#pragma unroll
      for (int j = 0; j < 4; ++j) {
        int row = mf * 16 + fg * 4 + j;        // 0..63 local
        int mg = m0 + wm * 64 + row;
        float v = acc[mf][nf][j] + bz;
        if (rope) {
          float p = __shfl_xor(v, 1);
          F2 cs = tab[(mg & 4095) * 16 + (d >> 1)];
          v = (d & 1) ? fmaf(v, cs.c, p * cs.s) : fmaf(v, cs.c, -(p * cs.s));
        }
        if (which == 0) v *= 0.125f;
        W[row * 64 + (((d >> 3) ^ (row & 7)) << 3) + (d & 7)] = f2b(v);
      }
    }
  }
  asm volatile("s_waitcnt lgkmcnt(0)" ::: "memory");
  __builtin_amdgcn_sched_barrier(0);
  size_t gbase = ((size_t)(bn * 16 + hh) * 256 + wm * 64) * 64;
#pragma unroll
  for (int it = 0; it < 8; ++it) {
    int r = it * 8 + (lane >> 3);
    int ch = (lane & 7) ^ (r & 7);
    s16x8 vv = *(const s16x8*)&W[r * 64 + ch * 8];
    *(s16x8*)&dst[gbase + r * 64 + (lane & 7) * 8] = vv;
  }
}

// ---------------- kernel 4: attention per (bn, h), 8 waves (unchanged r8) ---------------
__global__ __launch_bounds__(512, 1) void k_attn(
    const unsigned short* __restrict__ qbuf,
    const unsigned short* __restrict__ kbuf,
    const unsigned short* __restrict__ vbuf,
    unsigned short* __restrict__ xbuf) {
  __shared__ __align__(16) unsigned short Kl[256 * 64];
  __shared__ __align__(16) unsigned short Vt[64 * 264];
  __shared__ __align__(16) unsigned short Pl[8][16 * 264];
  int gb = blockIdx.x;                 // 1024 = (bn<<4)|h
  size_t base = (size_t)gb * (256 * 64);
  const unsigned short* Q = qbuf + base;
  const unsigned short* K = kbuf + base;
  const unsigned short* V = vbuf + base;
  int bn = gb >> 4, h = gb & 15;
  int tid = threadIdx.x, wid = tid >> 6, lane = tid & 63;
  int fr = lane & 15, fg = lane >> 4;

#pragma unroll
  for (int tt = 0; tt < 4; ++tt) {
    int t = wid * 4 + tt;
    int r = t * 8 + (lane >> 3);
    int csrc = (lane & 7) ^ (r & 7);
    gll16(K + r * 64 + csrc * 8, &Kl[t * 512]);
  }
  {
    int rv = tid >> 1, chalf = (tid & 1) * 32;
#pragma unroll
    for (int c8 = 0; c8 < 4; ++c8) {
      s16x8 vv = *(const s16x8*)&V[rv * 64 + chalf + c8 * 8];
#pragma unroll
      for (int j = 0; j < 8; ++j)
        Vt[(chalf + c8 * 8 + j) * 264 + rv] = (unsigned short)vv[j];
    }
  }
  __syncthreads();

  unsigned short* P = Pl[wid];
  int f7 = fr & 7;
  int c0 = (fg ^ f7) * 8;
  int c1 = ((4 + fg) ^ f7) * 8;
  for (int mtile = 0; mtile < 2; ++mtile) {
    int q0 = wid * 32 + mtile * 16;
    s16x8 qa0 = *(const s16x8*)&Q[(q0 + fr) * 64 + fg * 8];
    s16x8 qa1 = *(const s16x8*)&Q[(q0 + fr) * 64 + 32 + fg * 8];
    f32x4 sc[16] = {};
#pragma unroll
    for (int nt = 0; nt < 16; ++nt) {
      int rr = nt * 16 + fr;
      s16x8 kb0 = *(const s16x8*)&Kl[rr * 64 + c0];
      sc[nt] = mfma16(qa0, kb0, sc[nt]);
      s16x8 kb1 = *(const s16x8*)&Kl[rr * 64 + c1];
      sc[nt] = mfma16(qa1, kb1, sc[nt]);
    }
    float rs[4];
#pragma unroll
    for (int j = 0; j < 4; ++j) {
      float m = sc[0][j];
#pragma unroll
      for (int nt = 1; nt < 16; ++nt) m = fmaxf(m, sc[nt][j]);
      m = fmaxf(m, __shfl_xor(m, 1));
      m = fmaxf(m, __shfl_xor(m, 2));
      m = fmaxf(m, __shfl_xor(m, 4));
      m = fmaxf(m, __shfl_xor(m, 8));
      float sum = 0.f;
#pragma unroll
      for (int nt = 0; nt < 16; ++nt) {
        float p = __expf(sc[nt][j] - m);
        sum += p;
        P[(fg * 4 + j) * 264 + nt * 16 + fr] = f2b(p);
      }
      sum += __shfl_xor(sum, 1);
      sum += __shfl_xor(sum, 2);
      sum += __shfl_xor(sum, 4);
      sum += __shfl_xor(sum, 8);
      rs[j] = 1.0f / sum;
    }
    f32x4 o[4] = {};
#pragma unroll
    for (int ks = 0; ks < 8; ++ks) {
      s16x8 pa = *(const s16x8*)&P[fr * 264 + ks * 32 + fg * 8];
#pragma unroll
      for (int nt = 0; nt < 4; ++nt) {
        s16x8 vb = *(const s16x8*)&Vt[(nt * 16 + fr) * 264 + ks * 32 + fg * 8];
        o[nt] = mfma16(pa, vb, o[nt]);
      }
    }
#pragma unroll
    for (int nt = 0; nt < 4; ++nt)
#pragma unroll
      for (int j = 0; j < 4; ++j) {
        int srow = q0 + fg * 4 + j;
        int d = nt * 16 + fr;
        xbuf[((size_t)(bn * 256 + srow)) * 1024 + h * 64 + d] = f2b(o[nt][j] * rs[j]);
      }
  }
}

// ---------------- kernel 5: output GEMM + bo (f32 out), 16 waves ------------------------
__global__ __launch_bounds__(1024, 1) void k_out(
    const unsigned short* __restrict__ Xb,
    const unsigned short* __restrict__ WT,
    const float* __restrict__ bo,
    float* __restrict__ out) {
  __shared__ __align__(16) unsigned short S[65536];
  int bid = blockIdx.x;                        // 256 = 64 mt x 4 nt
  int swz = (bid & 7) * 32 + (bid >> 3);
  int mt = swz >> 2, nt = swz & 3;
  int m0 = mt * 256, n0 = nt * 256;
  int tid = threadIdx.x, wid = tid >> 6, lane = tid & 63;
  int fr = lane & 15, fg = lane >> 4;
  int wm = wid >> 2, wn = wid & 3;

  f32x4 acc[4][4] = {};
  gemm_core(Xb, WT, m0, n0, S, acc);

  // bounce epilogue, f32, two 32-row passes per wave (8 KB region), chunk-swizzled
  float* Wf = (float*)S + wid * 2048;
#pragma unroll
  for (int p = 0; p < 2; ++p) {
#pragma unroll
    for (int nf = 0; nf < 4; ++nf) {
      int d = nf * 16 + fr;
      float bz = bo[n0 + wn * 64 + d];
#pragma unroll
      for (int mh = 0; mh < 2; ++mh) {
        int mf = p * 2 + mh;
#pragma unroll
        for (int j = 0; j < 4; ++j) {
          int rloc = mh * 16 + fg * 4 + j;     // 0..31
          Wf[rloc * 64 + (((d >> 3) ^ (rloc & 7)) << 3) + (d & 7)] = acc[mf][nf][j] + bz;
        }
      }
    }
    asm volatile("s_waitcnt lgkmcnt(0)" ::: "memory");
    __builtin_amdgcn_sched_barrier(0);
#pragma unroll
    for (int it = 0; it < 8; ++it) {
      int rloc = it * 4 + (lane >> 4);         // 0..31
      int cpair = lane & 15;                   // d = cpair*4 .. +3
      int ch = (cpair >> 1) ^ (rloc & 7);
      f32x4 vv = *(const f32x4*)&Wf[rloc * 64 + ch * 8 + (cpair & 1) * 4];
      int mg = m0 + wm * 64 + p * 32 + rloc;
      *(f32x4*)&out[(size_t)mg * 1024 + n0 + wn * 64 + cpair * 4] = vv;
    }
    asm volatile("s_waitcnt lgkmcnt(0)" ::: "memory");
    __builtin_amdgcn_sched_barrier(0);
  }
}

extern "C" void kernel_launch(void* const* d_in, const int* in_sizes, int n_in,
                              void* d_out, int out_size, void* d_ws, size_t ws_size,
                              hipStream_t stream) {
  const float* Xq  = (const float*)d_in[0];
  const float* Xkv = (const float*)d_in[1];
  const float* Wq  = (const float*)d_in[2];
  const float* bq  = (const float*)d_in[3];
  const float* Wk  = (const float*)d_in[4];
  const float* bk  = (const float*)d_in[5];
  const float* Wv  = (const float*)d_in[6];
  const float* bv  = (const float*)d_in[7];
  const float* Wo  = (const float*)d_in[8];
  const float* bo  = (const float*)d_in[9];
  float* out = (float*)d_out;

  char* ws = (char*)d_ws;
  size_t off = 0;
  F2* tab = (F2*)(ws + off);                           off += (size_t)65536 * sizeof(F2);
  unsigned short* WTqkv = (unsigned short*)(ws + off); off += (size_t)3 * 1048576 * 2;
  unsigned short* WTo   = (unsigned short*)(ws + off); off += (size_t)1048576 * 2;
  unsigned short* Xqb   = (unsigned short*)(ws + off); off += (size_t)16777216 * 2;
  unsigned short* Xkvb  = (unsigned short*)(ws + off); off += (size_t)16777216 * 2;
  unsigned short* qb = (unsigned short*)(ws + off); off += (size_t)16777216 * 2;
  unsigned short* kb = (unsigned short*)(ws + off); off += (size_t)16777216 * 2;
  unsigned short* vb = (unsigned short*)(ws + off); off += (size_t)16777216 * 2;
  unsigned short* xb = Xqb;   // alias: Xq_bf16 dead after k_qkv

  k_prep<<<4352, 256, 0, stream>>>(Xq, Xkv, Xqb, Xkvb, tab);
  k_transpose<<<dim3(32, 32, 4), dim3(32, 32), 0, stream>>>(Wq, Wk, Wv, Wo, WTqkv, WTo);
  k_qkv<<<768, 1024, 0, stream>>>(Xqb, Xkvb, WTqkv, bq, bk, bv, tab, qb, kb, vb);
  k_attn<<<1024, 512, 0, stream>>>(qb, kb, vb, xb);
  k_out<<<256, 1024, 0, stream>>>(xb, WTo, bo, out);
}

// Round 10
// 260.981 us; speedup vs baseline: 1.0825x; 1.0825x over previous
//
#include <hip/hip_runtime.h>

typedef __attribute__((ext_vector_type(4))) float f32x4;
typedef __attribute__((ext_vector_type(8))) short s16x8;
typedef __attribute__((ext_vector_type(4))) unsigned short u16x4;

struct F2 { float c, s; };

__device__ __forceinline__ unsigned short f2b(float f) {
  unsigned u = __builtin_bit_cast(unsigned, f);
  u += 0x7FFFu + ((u >> 16) & 1u);
  return (unsigned short)(u >> 16);
}
__device__ __forceinline__ void gll16(const void* g, void* l) {
  __builtin_amdgcn_global_load_lds(
      (const __attribute__((address_space(1))) unsigned int*)g,
      (__attribute__((address_space(3))) unsigned int*)l, 16, 0, 0);
}
__device__ __forceinline__ f32x4 mfma16(s16x8 a, s16x8 b, f32x4 c) {
  return __builtin_amdgcn_mfma_f32_16x16x32_bf16(a, b, c, 0, 0, 0);
}

// ---------------- kernel 0: fused prep — input f32->bf16 cvt + RoPE sin/cos table -------
__global__ void k_prep(const float* __restrict__ Xq, const float* __restrict__ Xkv,
                       unsigned short* __restrict__ Xqb, unsigned short* __restrict__ Xkvb,
                       F2* __restrict__ tab) {
  int b = blockIdx.x;
  if (b < 4096) {
    const float* src = (b < 2048) ? Xq : Xkv;
    unsigned short* dst = (b < 2048) ? Xqb : Xkvb;
    int i = (b & 2047) * 256 + threadIdx.x;
    for (; i < 4194304; i += 2048 * 256) {
      f32x4 v = ((const f32x4*)src)[i];
      u16x4 o;
      o.x = f2b(v.x); o.y = f2b(v.y); o.z = f2b(v.z); o.w = f2b(v.w);
      ((u16x4*)dst)[i] = o;
    }
  } else {
    int idx = (b - 4096) * 256 + threadIdx.x;   // 65536 entries
    int pos = idx >> 4, fi = idx & 15;
    double inv = exp((double)fi * (-9.210340371976184 / 16.0));  // 10000^(-fi/16)
    double a = (double)pos * inv;
    F2 r; r.c = (float)cos(a); r.s = (float)sin(a);
    tab[idx] = r;
  }
}

// ---------------- kernel 2: transpose weights f32 [K][N] -> bf16 [N][K] -----------------
__global__ void k_transpose(const float* __restrict__ wq,
                            const float* __restrict__ wk,
                            const float* __restrict__ wv,
                            const float* __restrict__ wo,
                            unsigned short* __restrict__ wtqkv,
                            unsigned short* __restrict__ wto) {
  __shared__ unsigned short tile[32][33];
  int z = blockIdx.z;
  const float* src = (z == 0) ? wq : (z == 1) ? wk : (z == 2) ? wv : wo;
  unsigned short* dst = (z < 3) ? (wtqkv + (size_t)z * 1048576) : wto;
  int bx = blockIdx.x * 32, by = blockIdx.y * 32;
  tile[threadIdx.y][threadIdx.x] = f2b(src[(size_t)(by + threadIdx.y) * 1024 + bx + threadIdx.x]);
  __syncthreads();
  dst[(size_t)(bx + threadIdx.y) * 1024 + by + threadIdx.x] = tile[threadIdx.x][threadIdx.y];
}

// ---------------- kernel 3: QKV GEMM — round-2 2-phase 128^2 structure + T2 swizzle -----
// 256 threads / 4 waves, 32 KB LDS single-buffered, 2 barriers per K-tile, multi-block/CU
// (block-level TLP is the overlap mechanism). T2: granule ^= (row&7) on gll16 source and
// ds_read offset (rule #21: linear LDS dest + inverse-swizzled source + swizzled read).
__global__ __launch_bounds__(256, 2) void k_qkv(
    const unsigned short* __restrict__ Xq,
    const unsigned short* __restrict__ Xkv,
    const unsigned short* __restrict__ WT,
    const float* __restrict__ bq,
    const float* __restrict__ bk,
    const float* __restrict__ bv,
    const F2* __restrict__ tab,
    unsigned short* __restrict__ qbuf,
    unsigned short* __restrict__ kbuf,
    unsigned short* __restrict__ vbuf) {
  __shared__ __align__(16) unsigned short S[16384];   // Al[128*64] + Bl[128*64] = 32 KB
  unsigned short* Al = S;
  unsigned short* Bl = S + 8192;
  int bid = blockIdx.x;                       // 3072
  int swz = (bid & 7) * 384 + (bid >> 3);     // XCD swizzle, bijective (3072 % 8 == 0)
  int mt = swz / 24, nt = swz % 24;
  int m0 = mt * 128, n0 = nt * 128;
  int which = n0 >> 10;                       // 0=q 1=k 2=v
  const unsigned short* X = (which == 0) ? Xq : Xkv;
  const float* bias = (which == 0) ? bq : (which == 1) ? bk : bv;
  unsigned short* dst = (which == 0) ? qbuf : (which == 1) ? kbuf : vbuf;
  int n0l = n0 & 1023;
  int tid = threadIdx.x, wid = tid >> 6, lane = tid & 63;
  int fr = lane & 15, fg = lane >> 4, f7 = fr & 7;
  int wr = (wid >> 1) * 64, wc = (wid & 1) * 64;
  int sr = lane >> 3, scp = lane & 7;
  int g0 = (fg ^ f7) * 8, g1 = ((4 + fg) ^ f7) * 8;

  f32x4 acc[4][4] = {};
  for (int kt = 0; kt < 16; ++kt) {
    int kb = kt * 64;
#pragma unroll
    for (int tt = 0; tt < 4; ++tt) {
      int t = wid * 4 + tt;
      int row = t * 8 + sr;
      int cs = (scp ^ (row & 7)) * 8;         // inverse-swizzled source granule
      gll16(X  + (size_t)(m0 + row) * 1024 + kb + cs, &Al[t * 512]);
      gll16(WT + (size_t)(n0 + row) * 1024 + kb + cs, &Bl[t * 512]);
    }
    __syncthreads();
#pragma unroll
    for (int ks = 0; ks < 2; ++ks) {
      int gk = ks ? g1 : g0;                  // swizzled read granule
      s16x8 af[4], bfr[4];
#pragma unroll
      for (int i = 0; i < 4; ++i) af[i]  = *(const s16x8*)&Al[(wr + i * 16 + fr) * 64 + gk];
#pragma unroll
      for (int i = 0; i < 4; ++i) bfr[i] = *(const s16x8*)&Bl[(wc + i * 16 + fr) * 64 + gk];
#pragma unroll
      for (int mi = 0; mi < 4; ++mi)
#pragma unroll
        for (int ni = 0; ni < 4; ++ni)
          acc[mi][ni] = mfma16(af[mi], bfr[ni], acc[mi][ni]);
    }
    __syncthreads();
  }

  // epilogue: bias + RoPE + scale, LDS-bounce (per-wave 8 KB of S), coalesced 16B stores.
  // wave covers rows m0+wr..+63, cols n0+wc..+63 (one 64x64 head-block).
  unsigned short* W = S + wid * 4096;
  int hh = (n0l + wc) >> 6;                   // head of this wave's columns
  int rbase = m0 + wr;                        // 64-aligned; within one bn block of 256
  int bn = rbase >> 8;
#pragma unroll
  for (int nf = 0; nf < 4; ++nf) {
    int d = nf * 16 + fr;                     // 0..63 within head
    int col = n0l + wc + d;
    float bz = bias[col];
    bool rope = (which < 2) && (nf < 2);      // d<32 <=> nf<2, wave-uniform
#pragma unroll
    for (int mf = 0; mf < 4; ++mf) {
#pragma unroll
      for (int j = 0; j < 4; ++j) {
        int row = mf * 16 + fg * 4 + j;       // 0..63 local
        int mg = rbase + row;
        float v = acc[mf][nf][j] + bz;
        if (rope) {
          float p = __shfl_xor(v, 1);
          F2 cs = tab[(mg & 4095) * 16 + (d >> 1)];
          v = (d & 1) ? fmaf(v, cs.c, p * cs.s) : fmaf(v, cs.c, -(p * cs.s));
        }
        if (which == 0) v *= 0.125f;
        W[row * 64 + (((d >> 3) ^ (row & 7)) << 3) + (d & 7)] = f2b(v);
      }
    }
  }
  asm volatile("s_waitcnt lgkmcnt(0)" ::: "memory");
  __builtin_amdgcn_sched_barrier(0);
  size_t gbase = ((size_t)(bn * 16 + hh) * 256 + (rbase & 255)) * 64;
#pragma unroll
  for (int it = 0; it < 8; ++it) {
    int r = it * 8 + (lane >> 3);
    int ch = (lane & 7) ^ (r & 7);
    s16x8 vv = *(const s16x8*)&W[r * 64 + ch * 8];
    *(s16x8*)&dst[gbase + r * 64 + (lane & 7) * 8] = vv;
  }
}

// ---------------- 8-phase 256x256 GEMM core (round-5, for k_out) ------------------------
__device__ __forceinline__ void gemm_core(
    const unsigned short* __restrict__ Ag, const unsigned short* __restrict__ Bg,
    int m0, int n0, unsigned short* Sh, f32x4 (&acc)[8][4]) {
  const int tid = threadIdx.x, wid = tid >> 6, lane = tid & 63;
  const int fr = lane & 15, fg = lane >> 4, f7 = fr & 7;
  const int wm = wid >> 2, wn = wid & 3;
  const int rowoff = lane >> 3;
  const int lanecol = ((lane & 7) ^ rowoff) * 8;
  const int g0 = (fg ^ f7) * 8, g1 = ((4 + fg) ^ f7) * 8;

  auto SA = [&](int T, int ah) {
    unsigned short* dstb = Sh + (T & 1) * 32768;
#pragma unroll
    for (int i = 0; i < 2; ++i) {
      int rloc = ah * 128 + (wid * 2 + i) * 8;
      gll16(Ag + (size_t)(m0 + rloc + rowoff) * 1024 + T * 64 + lanecol, dstb + rloc * 64);
    }
  };
  auto SB = [&](int T, int bh) {
    unsigned short* dstb = Sh + (T & 1) * 32768 + 16384;
#pragma unroll
    for (int i = 0; i < 2; ++i) {
      int rloc = bh * 128 + (wid * 2 + i) * 8;
      gll16(Bg + (size_t)(n0 + rloc + rowoff) * 1024 + T * 64 + lanecol, dstb + rloc * 64);
    }
  };

  SA(0, 0); SA(0, 1); SB(0, 0); SB(0, 1); SA(1, 0); SA(1, 1);
  asm volatile("s_waitcnt vmcnt(4)" ::: "memory");
  __builtin_amdgcn_sched_barrier(0);
  __builtin_amdgcn_s_barrier();

  for (int t = 0; t < 16; ++t) {
    const unsigned short* bufA = Sh + (t & 1) * 32768;
    const unsigned short* bufB = bufA + 16384;
    s16x8 a0[4][2], a1[4][2], b0[2][2], b1[2][2];
#pragma unroll
    for (int mf = 0; mf < 4; ++mf) {
      const unsigned short* r = &bufA[(wm * 128 + mf * 16 + fr) * 64];
      a0[mf][0] = *(const s16x8*)&r[g0];
      a0[mf][1] = *(const s16x8*)&r[g1];
    }
#pragma unroll
    for (int nf = 0; nf < 2; ++nf) {
      const unsigned short* r = &bufB[(wn * 64 + nf * 16 + fr) * 64];
      b0[nf][0] = *(const s16x8*)&r[g0];
      b0[nf][1] = *(const s16x8*)&r[g1];
    }
    if (t + 1 < 16) SB(t + 1, 0);
    __builtin_amdgcn_s_barrier();
    asm volatile("s_waitcnt lgkmcnt(0)" ::: "memory");
    __builtin_amdgcn_sched_barrier(0);
    __builtin_amdgcn_s_setprio(1);
#pragma unroll
    for (int mf = 0; mf < 4; ++mf)
#pragma unroll
      for (int nf = 0; nf < 2; ++nf) {
        acc[mf][nf] = mfma16(a0[mf][0], b0[nf][0], acc[mf][nf]);
        acc[mf][nf] = mfma16(a0[mf][1], b0[nf][1], acc[mf][nf]);
      }
    __builtin_amdgcn_s_setprio(0);
    __builtin_amdgcn_s_barrier();
#pragma unroll
    for (int mf = 0; mf < 4; ++mf) {
      const unsigned short* r = &bufA[(wm * 128 + 64 + mf * 16 + fr) * 64];
      a1[mf][0] = *(const s16x8*)&r[g0];
      a1[mf][1] = *(const s16x8*)&r[g1];
    }
    if (t + 1 < 16) SB(t + 1, 1);
    __builtin_amdgcn_s_barrier();
    asm volatile("s_waitcnt lgkmcnt(0)" ::: "memory");
    __builtin_amdgcn_sched_barrier(0);
    __builtin_amdgcn_s_setprio(1);
#pragma unroll
    for (int mf = 0; mf < 4; ++mf)
#pragma unroll
      for (int nf = 0; nf < 2; ++nf) {
        acc[4 + mf][nf] = mfma16(a1[mf][0], b0[nf][0], acc[4 + mf][nf]);
        acc[4 + mf][nf] = mfma16(a1[mf][1], b0[nf][1], acc[4 + mf][nf]);
      }
    __builtin_amdgcn_s_setprio(0);
    __builtin_amdgcn_s_barrier();
#pragma unroll
    for (int nf = 0; nf < 2; ++nf) {
      const unsigned short* r = &bufB[(wn * 64 + 32 + nf * 16 + fr) * 64];
      b1[nf][0] = *(const s16x8*)&r[g0];
      b1[nf][1] = *(const s16x8*)&r[g1];
    }
    if (t + 2 < 16) SA(t + 2, 0);
    __builtin_amdgcn_s_barrier();
    asm volatile("s_waitcnt lgkmcnt(0)" ::: "memory");
    __builtin_amdgcn_sched_barrier(0);
    __builtin_amdgcn_s_setprio(1);
#pragma unroll
    for (int mf = 0; mf < 4; ++mf)
#pragma unroll
      for (int nf = 0; nf < 2; ++nf) {
        acc[4 + mf][2 + nf] = mfma16(a1[mf][0], b1[nf][0], acc[4 + mf][2 + nf]);
        acc[4 + mf][2 + nf] = mfma16(a1[mf][1], b1[nf][1], acc[4 + mf][2 + nf]);
      }
    __builtin_amdgcn_s_setprio(0);
    __builtin_amdgcn_s_barrier();
    if (t + 2 < 16) SA(t + 2, 1);
    if (t < 14) asm volatile("s_waitcnt vmcnt(4)" ::: "memory");
    else        asm volatile("s_waitcnt vmcnt(0)" ::: "memory");
    __builtin_amdgcn_sched_barrier(0);
    __builtin_amdgcn_s_barrier();
    __builtin_amdgcn_s_setprio(1);
#pragma unroll
    for (int mf = 0; mf < 4; ++mf)
#pragma unroll
      for (int nf = 0; nf < 2; ++nf) {
        acc[mf][2 + nf] = mfma16(a0[mf][0], b1[nf][0], acc[mf][2 + nf]);
        acc[mf][2 + nf] = mfma16(a0[mf][1], b1[nf][1], acc[mf][2 + nf]);
      }
    __builtin_amdgcn_s_setprio(0);
    __builtin_amdgcn_s_barrier();
  }
}

// ---------------- kernel 4: attention per (bn, h), 8 waves (r8) -------------------------
__global__ __launch_bounds__(512, 1) void k_attn(
    const unsigned short* __restrict__ qbuf,
    const unsigned short* __restrict__ kbuf,
    const unsigned short* __restrict__ vbuf,
    unsigned short* __restrict__ xbuf) {
  __shared__ __align__(16) unsigned short Kl[256 * 64];
  __shared__ __align__(16) unsigned short Vt[64 * 264];
  __shared__ __align__(16) unsigned short Pl[8][16 * 264];
  int gb = blockIdx.x;                 // 1024 = (bn<<4)|h
  size_t base = (size_t)gb * (256 * 64);
  const unsigned short* Q = qbuf + base;
  const unsigned short* K = kbuf + base;
  const unsigned short* V = vbuf + base;
  int bn = gb >> 4, h = gb & 15;
  int tid = threadIdx.x, wid = tid >> 6, lane = tid & 63;
  int fr = lane & 15, fg = lane >> 4;

#pragma unroll
  for (int tt = 0; tt < 4; ++tt) {
    int t = wid * 4 + tt;
    int r = t * 8 + (lane >> 3);
    int csrc = (lane & 7) ^ (r & 7);
    gll16(K + r * 64 + csrc * 8, &Kl[t * 512]);
  }
  {
    int rv = tid >> 1, chalf = (tid & 1) * 32;
#pragma unroll
    for (int c8 = 0; c8 < 4; ++c8) {
      s16x8 vv = *(const s16x8*)&V[rv * 64 + chalf + c8 * 8];
#pragma unroll
      for (int j = 0; j < 8; ++j)
        Vt[(chalf + c8 * 8 + j) * 264 + rv] = (unsigned short)vv[j];
    }
  }
  __syncthreads();

  unsigned short* P = Pl[wid];
  int f7 = fr & 7;
  int c0 = (fg ^ f7) * 8;
  int c1 = ((4 + fg) ^ f7) * 8;
  for (int mtile = 0; mtile < 2; ++mtile) {
    int q0 = wid * 32 + mtile * 16;
    s16x8 qa0 = *(const s16x8*)&Q[(q0 + fr) * 64 + fg * 8];
    s16x8 qa1 = *(const s16x8*)&Q[(q0 + fr) * 64 + 32 + fg * 8];
    f32x4 sc[16] = {};
#pragma unroll
    for (int nt = 0; nt < 16; ++nt) {
      int rr = nt * 16 + fr;
      s16x8 kb0 = *(const s16x8*)&Kl[rr * 64 + c0];
      sc[nt] = mfma16(qa0, kb0, sc[nt]);
      s16x8 kb1 = *(const s16x8*)&Kl[rr * 64 + c1];
      sc[nt] = mfma16(qa1, kb1, sc[nt]);
    }
    float rs[4];
#pragma unroll
    for (int j = 0; j < 4; ++j) {
      float m = sc[0][j];
#pragma unroll
      for (int nt = 1; nt < 16; ++nt) m = fmaxf(m, sc[nt][j]);
      m = fmaxf(m, __shfl_xor(m, 1));
      m = fmaxf(m, __shfl_xor(m, 2));
      m = fmaxf(m, __shfl_xor(m, 4));
      m = fmaxf(m, __shfl_xor(m, 8));
      float sum = 0.f;
#pragma unroll
      for (int nt = 0; nt < 16; ++nt) {
        float p = __expf(sc[nt][j] - m);
        sum += p;
        P[(fg * 4 + j) * 264 + nt * 16 + fr] = f2b(p);
      }
      sum += __shfl_xor(sum, 1);
      sum += __shfl_xor(sum, 2);
      sum += __shfl_xor(sum, 4);
      sum += __shfl_xor(sum, 8);
      rs[j] = 1.0f / sum;
    }
    f32x4 o[4] = {};
#pragma unroll
    for (int ks = 0; ks < 8; ++ks) {
      s16x8 pa = *(const s16x8*)&P[fr * 264 + ks * 32 + fg * 8];
#pragma unroll
      for (int nt = 0; nt < 4; ++nt) {
        s16x8 vb = *(const s16x8*)&Vt[(nt * 16 + fr) * 264 + ks * 32 + fg * 8];
        o[nt] = mfma16(pa, vb, o[nt]);
      }
    }
#pragma unroll
    for (int nt = 0; nt < 4; ++nt)
#pragma unroll
      for (int j = 0; j < 4; ++j) {
        int srow = q0 + fg * 4 + j;
        int d = nt * 16 + fr;
        xbuf[((size_t)(bn * 256 + srow)) * 1024 + h * 64 + d] = f2b(o[nt][j] * rs[j]);
      }
  }
}

// ---------------- kernel 5: output GEMM + bo (f32 out), r8 ------------------------------
__global__ __launch_bounds__(512, 1) void k_out(
    const unsigned short* __restrict__ Xb,
    const unsigned short* __restrict__ WT,
    const float* __restrict__ bo,
    float* __restrict__ out) {
  __shared__ __align__(16) unsigned short S[65536];
  int bid = blockIdx.x;                        // 256 = 64 mt x 4 nt
  int swz = (bid & 7) * 32 + (bid >> 3);
  int mt = swz >> 2, nt = swz & 3;
  int m0 = mt * 256, n0 = nt * 256;
  int tid = threadIdx.x, wid = tid >> 6, lane = tid & 63;
  int fr = lane & 15, fg = lane >> 4;
  int wm = wid >> 2, wn = wid & 3;

  f32x4 acc[8][4] = {};
  gemm_core(Xb, WT, m0, n0, S, acc);

  float* Wf = (float*)S + wid * 4096;
#pragma unroll
  for (int p = 0; p < 2; ++p) {
#pragma unroll
    for (int nf = 0; nf < 4; ++nf) {
      int d = nf * 16 + fr;
      float bz = bo[n0 + wn * 64 + d];
#pragma unroll
      for (int mf = 0; mf < 4; ++mf) {
#pragma unroll
        for (int j = 0; j < 4; ++j) {
          int row = mf * 16 + fg * 4 + j;
          Wf[row * 64 + d] = acc[p * 4 + mf][nf][j] + bz;
        }
      }
    }
    asm volatile("s_waitcnt lgkmcnt(0)" ::: "memory");
    __builtin_amdgcn_sched_barrier(0);
#pragma unroll
    for (int it = 0; it < 16; ++it) {
      int r = it * 4 + (lane >> 4);
      f32x4 vv = *(const f32x4*)&Wf[r * 64 + (lane & 15) * 4];
      int mg = m0 + wm * 128 + p * 64 + r;
      *(f32x4*)&out[(size_t)mg * 1024 + n0 + wn * 64 + (lane & 15) * 4] = vv;
    }
    asm volatile("s_waitcnt lgkmcnt(0)" ::: "memory");
    __builtin_amdgcn_sched_barrier(0);
  }
}

extern "C" void kernel_launch(void* const* d_in, const int* in_sizes, int n_in,
                              void* d_out, int out_size, void* d_ws, size_t ws_size,
                              hipStream_t stream) {
  const float* Xq  = (const float*)d_in[0];
  const float* Xkv = (const float*)d_in[1];
  const float* Wq  = (const float*)d_in[2];
  const float* bq  = (const float*)d_in[3];
  const float* Wk  = (const float*)d_in[4];
  const float* bk  = (const float*)d_in[5];
  const float* Wv  = (const float*)d_in[6];
  const float* bv  = (const float*)d_in[7];
  const float* Wo  = (const float*)d_in[8];
  const float* bo  = (const float*)d_in[9];
  float* out = (float*)d_out;

  char* ws = (char*)d_ws;
  size_t off = 0;
  F2* tab = (F2*)(ws + off);                           off += (size_t)65536 * sizeof(F2);
  unsigned short* WTqkv = (unsigned short*)(ws + off); off += (size_t)3 * 1048576 * 2;
  unsigned short* WTo   = (unsigned short*)(ws + off); off += (size_t)1048576 * 2;
  unsigned short* Xqb   = (unsigned short*)(ws + off); off += (size_t)16777216 * 2;
  unsigned short* Xkvb  = (unsigned short*)(ws + off); off += (size_t)16777216 * 2;
  unsigned short* qb = (unsigned short*)(ws + off); off += (size_t)16777216 * 2;
  unsigned short* kb = (unsigned short*)(ws + off); off += (size_t)16777216 * 2;
  unsigned short* vb = (unsigned short*)(ws + off); off += (size_t)16777216 * 2;
  unsigned short* xb = Xqb;   // alias: Xq_bf16 dead after k_qkv

  k_prep<<<4352, 256, 0, stream>>>(Xq, Xkv, Xqb, Xkvb, tab);
  k_transpose<<<dim3(32, 32, 4), dim3(32, 32), 0, stream>>>(Wq, Wk, Wv, Wo, WTqkv, WTo);
  k_qkv<<<3072, 256, 0, stream>>>(Xqb, Xkvb, WTqkv, bq, bk, bv, tab, qb, kb, vb);
  k_attn<<<1024, 512, 0, stream>>>(qb, kb, vb, xb);
  k_out<<<256, 512, 0, stream>>>(xb, WTo, bo, out);
}

// Round 11
// 259.224 us; speedup vs baseline: 1.0899x; 1.0068x over previous
//
#include <hip/hip_runtime.h>

typedef __attribute__((ext_vector_type(4))) float f32x4;
typedef __attribute__((ext_vector_type(8))) short s16x8;
typedef __attribute__((ext_vector_type(4))) unsigned short u16x4;

struct F2 { float c, s; };

__device__ __forceinline__ unsigned short f2b(float f) {
  unsigned u = __builtin_bit_cast(unsigned, f);
  u += 0x7FFFu + ((u >> 16) & 1u);
  return (unsigned short)(u >> 16);
}
__device__ __forceinline__ void gll16(const void* g, void* l) {
  __builtin_amdgcn_global_load_lds(
      (const __attribute__((address_space(1))) unsigned int*)g,
      (__attribute__((address_space(3))) unsigned int*)l, 16, 0, 0);
}
__device__ __forceinline__ f32x4 mfma16(s16x8 a, s16x8 b, f32x4 c) {
  return __builtin_amdgcn_mfma_f32_16x16x32_bf16(a, b, c, 0, 0, 0);
}

// ---------------- kernel 0: fused prep — input f32->bf16 cvt + RoPE sin/cos table -------
__global__ void k_prep(const float* __restrict__ Xq, const float* __restrict__ Xkv,
                       unsigned short* __restrict__ Xqb, unsigned short* __restrict__ Xkvb,
                       F2* __restrict__ tab) {
  int b = blockIdx.x;
  if (b < 4096) {
    const float* src = (b < 2048) ? Xq : Xkv;
    unsigned short* dst = (b < 2048) ? Xqb : Xkvb;
    int i = (b & 2047) * 256 + threadIdx.x;
    for (; i < 4194304; i += 2048 * 256) {
      f32x4 v = ((const f32x4*)src)[i];
      u16x4 o;
      o.x = f2b(v.x); o.y = f2b(v.y); o.z = f2b(v.z); o.w = f2b(v.w);
      ((u16x4*)dst)[i] = o;
    }
  } else {
    int idx = (b - 4096) * 256 + threadIdx.x;   // 65536 entries
    int pos = idx >> 4, fi = idx & 15;
    double inv = exp((double)fi * (-9.210340371976184 / 16.0));  // 10000^(-fi/16)
    double a = (double)pos * inv;
    F2 r; r.c = (float)cos(a); r.s = (float)sin(a);
    tab[idx] = r;
  }
}

// ---------------- kernel 2: transpose weights f32 [K][N] -> bf16 [N][K] -----------------
__global__ void k_transpose(const float* __restrict__ wq,
                            const float* __restrict__ wk,
                            const float* __restrict__ wv,
                            const float* __restrict__ wo,
                            unsigned short* __restrict__ wtqkv,
                            unsigned short* __restrict__ wto) {
  __shared__ unsigned short tile[32][33];
  int z = blockIdx.z;
  const float* src = (z == 0) ? wq : (z == 1) ? wk : (z == 2) ? wv : wo;
  unsigned short* dst = (z < 3) ? (wtqkv + (size_t)z * 1048576) : wto;
  int bx = blockIdx.x * 32, by = blockIdx.y * 32;
  tile[threadIdx.y][threadIdx.x] = f2b(src[(size_t)(by + threadIdx.y) * 1024 + bx + threadIdx.x]);
  __syncthreads();
  dst[(size_t)(bx + threadIdx.y) * 1024 + by + threadIdx.x] = tile[threadIdx.x][threadIdx.y];
}

// ---------------- kernel 3: QKV GEMM — 2-phase 128^2 + T2 swizzle (round-10 WIN) --------
__global__ __launch_bounds__(256, 2) void k_qkv(
    const unsigned short* __restrict__ Xq,
    const unsigned short* __restrict__ Xkv,
    const unsigned short* __restrict__ WT,
    const float* __restrict__ bq,
    const float* __restrict__ bk,
    const float* __restrict__ bv,
    const F2* __restrict__ tab,
    unsigned short* __restrict__ qbuf,
    unsigned short* __restrict__ kbuf,
    unsigned short* __restrict__ vbuf) {
  __shared__ __align__(16) unsigned short S[16384];   // Al[128*64] + Bl[128*64] = 32 KB
  unsigned short* Al = S;
  unsigned short* Bl = S + 8192;
  int bid = blockIdx.x;                       // 3072
  int swz = (bid & 7) * 384 + (bid >> 3);     // XCD swizzle, bijective (3072 % 8 == 0)
  int mt = swz / 24, nt = swz % 24;
  int m0 = mt * 128, n0 = nt * 128;
  int which = n0 >> 10;                       // 0=q 1=k 2=v
  const unsigned short* X = (which == 0) ? Xq : Xkv;
  const float* bias = (which == 0) ? bq : (which == 1) ? bk : bv;
  unsigned short* dst = (which == 0) ? qbuf : (which == 1) ? kbuf : vbuf;
  int n0l = n0 & 1023;
  int tid = threadIdx.x, wid = tid >> 6, lane = tid & 63;
  int fr = lane & 15, fg = lane >> 4, f7 = fr & 7;
  int wr = (wid >> 1) * 64, wc = (wid & 1) * 64;
  int sr = lane >> 3, scp = lane & 7;
  int g0 = (fg ^ f7) * 8, g1 = ((4 + fg) ^ f7) * 8;

  f32x4 acc[4][4] = {};
  for (int kt = 0; kt < 16; ++kt) {
    int kb = kt * 64;
#pragma unroll
    for (int tt = 0; tt < 4; ++tt) {
      int t = wid * 4 + tt;
      int row = t * 8 + sr;
      int cs = (scp ^ (row & 7)) * 8;         // inverse-swizzled source granule
      gll16(X  + (size_t)(m0 + row) * 1024 + kb + cs, &Al[t * 512]);
      gll16(WT + (size_t)(n0 + row) * 1024 + kb + cs, &Bl[t * 512]);
    }
    __syncthreads();
#pragma unroll
    for (int ks = 0; ks < 2; ++ks) {
      int gk = ks ? g1 : g0;                  // swizzled read granule
      s16x8 af[4], bfr[4];
#pragma unroll
      for (int i = 0; i < 4; ++i) af[i]  = *(const s16x8*)&Al[(wr + i * 16 + fr) * 64 + gk];
#pragma unroll
      for (int i = 0; i < 4; ++i) bfr[i] = *(const s16x8*)&Bl[(wc + i * 16 + fr) * 64 + gk];
#pragma unroll
      for (int mi = 0; mi < 4; ++mi)
#pragma unroll
        for (int ni = 0; ni < 4; ++ni)
          acc[mi][ni] = mfma16(af[mi], bfr[ni], acc[mi][ni]);
    }
    __syncthreads();
  }

  // epilogue: bias + RoPE + scale, LDS-bounce (per-wave 8 KB), coalesced 16B stores.
  unsigned short* W = S + wid * 4096;
  int hh = (n0l + wc) >> 6;
  int rbase = m0 + wr;
  int bn = rbase >> 8;
#pragma unroll
  for (int nf = 0; nf < 4; ++nf) {
    int d = nf * 16 + fr;
    int col = n0l + wc + d;
    float bz = bias[col];
    bool rope = (which < 2) && (nf < 2);
#pragma unroll
    for (int mf = 0; mf < 4; ++mf) {
#pragma unroll
      for (int j = 0; j < 4; ++j) {
        int row = mf * 16 + fg * 4 + j;
        int mg = rbase + row;
        float v = acc[mf][nf][j] + bz;
        if (rope) {
          float p = __shfl_xor(v, 1);
          F2 cs = tab[(mg & 4095) * 16 + (d >> 1)];
          v = (d & 1) ? fmaf(v, cs.c, p * cs.s) : fmaf(v, cs.c, -(p * cs.s));
        }
        if (which == 0) v *= 0.125f;
        W[row * 64 + (((d >> 3) ^ (row & 7)) << 3) + (d & 7)] = f2b(v);
      }
    }
  }
  asm volatile("s_waitcnt lgkmcnt(0)" ::: "memory");
  __builtin_amdgcn_sched_barrier(0);
  size_t gbase = ((size_t)(bn * 16 + hh) * 256 + (rbase & 255)) * 64;
#pragma unroll
  for (int it = 0; it < 8; ++it) {
    int r = it * 8 + (lane >> 3);
    int ch = (lane & 7) ^ (r & 7);
    s16x8 vv = *(const s16x8*)&W[r * 64 + ch * 8];
    *(s16x8*)&dst[gbase + r * 64 + (lane & 7) * 8] = vv;
  }
}

// ---------------- kernel 4: attention per (bn, h), 8 waves (r8) -------------------------
__global__ __launch_bounds__(512, 1) void k_attn(
    const unsigned short* __restrict__ qbuf,
    const unsigned short* __restrict__ kbuf,
    const unsigned short* __restrict__ vbuf,
    unsigned short* __restrict__ xbuf) {
  __shared__ __align__(16) unsigned short Kl[256 * 64];
  __shared__ __align__(16) unsigned short Vt[64 * 264];
  __shared__ __align__(16) unsigned short Pl[8][16 * 264];
  int gb = blockIdx.x;                 // 1024 = (bn<<4)|h
  size_t base = (size_t)gb * (256 * 64);
  const unsigned short* Q = qbuf + base;
  const unsigned short* K = kbuf + base;
  const unsigned short* V = vbuf + base;
  int bn = gb >> 4, h = gb & 15;
  int tid = threadIdx.x, wid = tid >> 6, lane = tid & 63;
  int fr = lane & 15, fg = lane >> 4;

#pragma unroll
  for (int tt = 0; tt < 4; ++tt) {
    int t = wid * 4 + tt;
    int r = t * 8 + (lane >> 3);
    int csrc = (lane & 7) ^ (r & 7);
    gll16(K + r * 64 + csrc * 8, &Kl[t * 512]);
  }
  {
    int rv = tid >> 1, chalf = (tid & 1) * 32;
#pragma unroll
    for (int c8 = 0; c8 < 4; ++c8) {
      s16x8 vv = *(const s16x8*)&V[rv * 64 + chalf + c8 * 8];
#pragma unroll
      for (int j = 0; j < 8; ++j)
        Vt[(chalf + c8 * 8 + j) * 264 + rv] = (unsigned short)vv[j];
    }
  }
  __syncthreads();

  unsigned short* P = Pl[wid];
  int f7 = fr & 7;
  int c0 = (fg ^ f7) * 8;
  int c1 = ((4 + fg) ^ f7) * 8;
  for (int mtile = 0; mtile < 2; ++mtile) {
    int q0 = wid * 32 + mtile * 16;
    s16x8 qa0 = *(const s16x8*)&Q[(q0 + fr) * 64 + fg * 8];
    s16x8 qa1 = *(const s16x8*)&Q[(q0 + fr) * 64 + 32 + fg * 8];
    f32x4 sc[16] = {};
#pragma unroll
    for (int nt = 0; nt < 16; ++nt) {
      int rr = nt * 16 + fr;
      s16x8 kb0 = *(const s16x8*)&Kl[rr * 64 + c0];
      sc[nt] = mfma16(qa0, kb0, sc[nt]);
      s16x8 kb1 = *(const s16x8*)&Kl[rr * 64 + c1];
      sc[nt] = mfma16(qa1, kb1, sc[nt]);
    }
    float rs[4];
#pragma unroll
    for (int j = 0; j < 4; ++j) {
      float m = sc[0][j];
#pragma unroll
      for (int nt = 1; nt < 16; ++nt) m = fmaxf(m, sc[nt][j]);
      m = fmaxf(m, __shfl_xor(m, 1));
      m = fmaxf(m, __shfl_xor(m, 2));
      m = fmaxf(m, __shfl_xor(m, 4));
      m = fmaxf(m, __shfl_xor(m, 8));
      float sum = 0.f;
#pragma unroll
      for (int nt = 0; nt < 16; ++nt) {
        float p = __expf(sc[nt][j] - m);
        sum += p;
        P[(fg * 4 + j) * 264 + nt * 16 + fr] = f2b(p);
      }
      sum += __shfl_xor(sum, 1);
      sum += __shfl_xor(sum, 2);
      sum += __shfl_xor(sum, 4);
      sum += __shfl_xor(sum, 8);
      rs[j] = 1.0f / sum;
    }
    f32x4 o[4] = {};
#pragma unroll
    for (int ks = 0; ks < 8; ++ks) {
      s16x8 pa = *(const s16x8*)&P[fr * 264 + ks * 32 + fg * 8];
#pragma unroll
      for (int nt = 0; nt < 4; ++nt) {
        s16x8 vb = *(const s16x8*)&Vt[(nt * 16 + fr) * 264 + ks * 32 + fg * 8];
        o[nt] = mfma16(pa, vb, o[nt]);
      }
    }
#pragma unroll
    for (int nt = 0; nt < 4; ++nt)
#pragma unroll
      for (int j = 0; j < 4; ++j) {
        int srow = q0 + fg * 4 + j;
        int d = nt * 16 + fr;
        xbuf[((size_t)(bn * 256 + srow)) * 1024 + h * 64 + d] = f2b(o[nt][j] * rs[j]);
      }
  }
}

// ---------------- kernel 5: output GEMM + bo (f32) — 2-phase 128^2 + T2 -----------------
__global__ __launch_bounds__(256, 2) void k_out(
    const unsigned short* __restrict__ Xb,
    const unsigned short* __restrict__ WT,
    const float* __restrict__ bo,
    float* __restrict__ out) {
  __shared__ __align__(16) unsigned short S[16384];   // 32 KB
  unsigned short* Al = S;
  unsigned short* Bl = S + 8192;
  int bid = blockIdx.x;                       // 1024 = 128 mt x 8 nt
  int swz = (bid & 7) * 128 + (bid >> 3);     // XCD swizzle, bijective
  int mt = swz >> 3, nt = swz & 7;
  int m0 = mt * 128, n0 = nt * 128;
  int tid = threadIdx.x, wid = tid >> 6, lane = tid & 63;
  int fr = lane & 15, fg = lane >> 4, f7 = fr & 7;
  int wr = (wid >> 1) * 64, wc = (wid & 1) * 64;
  int sr = lane >> 3, scp = lane & 7;
  int g0 = (fg ^ f7) * 8, g1 = ((4 + fg) ^ f7) * 8;

  f32x4 acc[4][4] = {};
  for (int kt = 0; kt < 16; ++kt) {
    int kb = kt * 64;
#pragma unroll
    for (int tt = 0; tt < 4; ++tt) {
      int t = wid * 4 + tt;
      int row = t * 8 + sr;
      int cs = (scp ^ (row & 7)) * 8;
      gll16(Xb + (size_t)(m0 + row) * 1024 + kb + cs, &Al[t * 512]);
      gll16(WT + (size_t)(n0 + row) * 1024 + kb + cs, &Bl[t * 512]);
    }
    __syncthreads();
#pragma unroll
    for (int ks = 0; ks < 2; ++ks) {
      int gk = ks ? g1 : g0;
      s16x8 af[4], bfr[4];
#pragma unroll
      for (int i = 0; i < 4; ++i) af[i]  = *(const s16x8*)&Al[(wr + i * 16 + fr) * 64 + gk];
#pragma unroll
      for (int i = 0; i < 4; ++i) bfr[i] = *(const s16x8*)&Bl[(wc + i * 16 + fr) * 64 + gk];
#pragma unroll
      for (int mi = 0; mi < 4; ++mi)
#pragma unroll
        for (int ni = 0; ni < 4; ++ni)
          acc[mi][ni] = mfma16(af[mi], bfr[ni], acc[mi][ni]);
    }
    __syncthreads();
  }

  // f32 bounce epilogue: two 32-row passes per wave through 8 KB (2048 floats),
  // 8-float-granule swizzle (r9-verified), f32x4 coalesced stores.
  float* Wf = (float*)S + wid * 2048;
  int rbase = m0 + wr;
#pragma unroll
  for (int p = 0; p < 2; ++p) {
#pragma unroll
    for (int nf = 0; nf < 4; ++nf) {
      int d = nf * 16 + fr;
      float bz = bo[n0 + wc + d];
#pragma unroll
      for (int mh = 0; mh < 2; ++mh) {
        int mf = p * 2 + mh;
#pragma unroll
        for (int j = 0; j < 4; ++j) {
          int rloc = mh * 16 + fg * 4 + j;     // 0..31
          Wf[rloc * 64 + (((d >> 3) ^ (rloc & 7)) << 3) + (d & 7)] = acc[mf][nf][j] + bz;
        }
      }
    }
    asm volatile("s_waitcnt lgkmcnt(0)" ::: "memory");
    __builtin_amdgcn_sched_barrier(0);
#pragma unroll
    for (int it = 0; it < 8; ++it) {
      int rloc = it * 4 + (lane >> 4);         // 0..31
      int cpair = lane & 15;                   // d = cpair*4 .. +3
      int ch = (cpair >> 1) ^ (rloc & 7);
      f32x4 vv = *(const f32x4*)&Wf[rloc * 64 + ch * 8 + (cpair & 1) * 4];
      int mg = rbase + p * 32 + rloc;
      *(f32x4*)&out[(size_t)mg * 1024 + n0 + wc + cpair * 4] = vv;
    }
    asm volatile("s_waitcnt lgkmcnt(0)" ::: "memory");
    __builtin_amdgcn_sched_barrier(0);
  }
}

extern "C" void kernel_launch(void* const* d_in, const int* in_sizes, int n_in,
                              void* d_out, int out_size, void* d_ws, size_t ws_size,
                              hipStream_t stream) {
  const float* Xq  = (const float*)d_in[0];
  const float* Xkv = (const float*)d_in[1];
  const float* Wq  = (const float*)d_in[2];
  const float* bq  = (const float*)d_in[3];
  const float* Wk  = (const float*)d_in[4];
  const float* bk  = (const float*)d_in[5];
  const float* Wv  = (const float*)d_in[6];
  const float* bv  = (const float*)d_in[7];
  const float* Wo  = (const float*)d_in[8];
  const float* bo  = (const float*)d_in[9];
  float* out = (float*)d_out;

  char* ws = (char*)d_ws;
  size_t off = 0;
  F2* tab = (F2*)(ws + off);                           off += (size_t)65536 * sizeof(F2);
  unsigned short* WTqkv = (unsigned short*)(ws + off); off += (size_t)3 * 1048576 * 2;
  unsigned short* WTo   = (unsigned short*)(ws + off); off += (size_t)1048576 * 2;
  unsigned short* Xqb   = (unsigned short*)(ws + off); off += (size_t)16777216 * 2;
  unsigned short* Xkvb  = (unsigned short*)(ws + off); off += (size_t)16777216 * 2;
  unsigned short* qb = (unsigned short*)(ws + off); off += (size_t)16777216 * 2;
  unsigned short* kb = (unsigned short*)(ws + off); off += (size_t)16777216 * 2;
  unsigned short* vb = (unsigned short*)(ws + off); off += (size_t)16777216 * 2;
  unsigned short* xb = Xqb;   // alias: Xq_bf16 dead after k_qkv

  k_prep<<<4352, 256, 0, stream>>>(Xq, Xkv, Xqb, Xkvb, tab);
  k_transpose<<<dim3(32, 32, 4), dim3(32, 32), 0, stream>>>(Wq, Wk, Wv, Wo, WTqkv, WTo);
  k_qkv<<<3072, 256, 0, stream>>>(Xqb, Xkvb, WTqkv, bq, bk, bv, tab, qb, kb, vb);
  k_attn<<<1024, 512, 0, stream>>>(qb, kb, vb, xb);
  k_out<<<1024, 256, 0, stream>>>(xb, WTo, bo, out);
}

// Round 12
// 252.233 us; speedup vs baseline: 1.1201x; 1.0277x over previous
//
#include <hip/hip_runtime.h>

typedef __attribute__((ext_vector_type(4))) float f32x4;
typedef __attribute__((ext_vector_type(8))) short s16x8;
typedef __attribute__((ext_vector_type(4))) unsigned short u16x4;

struct F2 { float c, s; };

__device__ __forceinline__ unsigned short f2b(float f) {
  unsigned u = __builtin_bit_cast(unsigned, f);
  u += 0x7FFFu + ((u >> 16) & 1u);
  return (unsigned short)(u >> 16);
}
__device__ __forceinline__ void gll16(const void* g, void* l) {
  __builtin_amdgcn_global_load_lds(
      (const __attribute__((address_space(1))) unsigned int*)g,
      (__attribute__((address_space(3))) unsigned int*)l, 16, 0, 0);
}
__device__ __forceinline__ f32x4 mfma16(s16x8 a, s16x8 b, f32x4 c) {
  return __builtin_amdgcn_mfma_f32_16x16x32_bf16(a, b, c, 0, 0, 0);
}

// ---------------- kernel 0: fused prep — cvt + sincos + weight transpose ----------------
// blocks 0..2047: Xq cvt; 2048..4095: Xkv cvt; 4096..4351: sincos table;
// 4352..8447: weight transpose f32 [K][N] -> bf16 [N][K] (4096 tiles of 32x32, 4 rows/thr).
__global__ void k_prep(const float* __restrict__ Xq, const float* __restrict__ Xkv,
                       unsigned short* __restrict__ Xqb, unsigned short* __restrict__ Xkvb,
                       F2* __restrict__ tab,
                       const float* __restrict__ wq, const float* __restrict__ wk,
                       const float* __restrict__ wv, const float* __restrict__ wo,
                       unsigned short* __restrict__ wtqkv, unsigned short* __restrict__ wto) {
  int b = blockIdx.x;
  if (b < 4096) {
    const float* src = (b < 2048) ? Xq : Xkv;
    unsigned short* dst = (b < 2048) ? Xqb : Xkvb;
    int i = (b & 2047) * 256 + threadIdx.x;
    for (; i < 4194304; i += 2048 * 256) {
      f32x4 v = ((const f32x4*)src)[i];
      u16x4 o;
      o.x = f2b(v.x); o.y = f2b(v.y); o.z = f2b(v.z); o.w = f2b(v.w);
      ((u16x4*)dst)[i] = o;
    }
  } else if (b < 4352) {
    int idx = (b - 4096) * 256 + threadIdx.x;   // 65536 entries
    int pos = idx >> 4, fi = idx & 15;
    double inv = exp((double)fi * (-9.210340371976184 / 16.0));  // 10000^(-fi/16)
    double a = (double)pos * inv;
    F2 r; r.c = (float)cos(a); r.s = (float)sin(a);
    tab[idx] = r;
  } else {
    __shared__ unsigned short tile[32][33];
    int tb = b - 4352;                          // 0..4095 = z*1024 + ty*32 + tx_tile
    int z = tb >> 10;                           // 0..3
    int tyx = tb & 1023;
    int bx = (tyx & 31) * 32, by = (tyx >> 5) * 32;
    const float* src = (z == 0) ? wq : (z == 1) ? wk : (z == 2) ? wv : wo;
    unsigned short* dst = (z < 3) ? (wtqkv + (size_t)z * 1048576) : wto;
    int tx = threadIdx.x & 31, ty = threadIdx.x >> 5;   // ty 0..7
#pragma unroll
    for (int r = 0; r < 4; ++r)
      tile[ty + r * 8][tx] = f2b(src[(size_t)(by + ty + r * 8) * 1024 + bx + tx]);
    __syncthreads();
#pragma unroll
    for (int r = 0; r < 4; ++r)
      dst[(size_t)(bx + ty + r * 8) * 1024 + by + tx] = tile[tx][ty + r * 8];
  }
}

// ---------------- kernel 3: QKV GEMM — 2-phase 128^2 + T2 swizzle (round-10 WIN) --------
__global__ __launch_bounds__(256, 2) void k_qkv(
    const unsigned short* __restrict__ Xq,
    const unsigned short* __restrict__ Xkv,
    const unsigned short* __restrict__ WT,
    const float* __restrict__ bq,
    const float* __restrict__ bk,
    const float* __restrict__ bv,
    const F2* __restrict__ tab,
    unsigned short* __restrict__ qbuf,
    unsigned short* __restrict__ kbuf,
    unsigned short* __restrict__ vbuf) {
  __shared__ __align__(16) unsigned short S[16384];   // Al[128*64] + Bl[128*64] = 32 KB
  unsigned short* Al = S;
  unsigned short* Bl = S + 8192;
  int bid = blockIdx.x;                       // 3072
  int swz = (bid & 7) * 384 + (bid >> 3);     // XCD swizzle, bijective (3072 % 8 == 0)
  int mt = swz / 24, nt = swz % 24;
  int m0 = mt * 128, n0 = nt * 128;
  int which = n0 >> 10;                       // 0=q 1=k 2=v
  const unsigned short* X = (which == 0) ? Xq : Xkv;
  const float* bias = (which == 0) ? bq : (which == 1) ? bk : bv;
  unsigned short* dst = (which == 0) ? qbuf : (which == 1) ? kbuf : vbuf;
  int n0l = n0 & 1023;
  int tid = threadIdx.x, wid = tid >> 6, lane = tid & 63;
  int fr = lane & 15, fg = lane >> 4, f7 = fr & 7;
  int wr = (wid >> 1) * 64, wc = (wid & 1) * 64;
  int sr = lane >> 3, scp = lane & 7;
  int g0 = (fg ^ f7) * 8, g1 = ((4 + fg) ^ f7) * 8;

  f32x4 acc[4][4] = {};
  for (int kt = 0; kt < 16; ++kt) {
    int kb = kt * 64;
#pragma unroll
    for (int tt = 0; tt < 4; ++tt) {
      int t = wid * 4 + tt;
      int row = t * 8 + sr;
      int cs = (scp ^ (row & 7)) * 8;         // inverse-swizzled source granule
      gll16(X  + (size_t)(m0 + row) * 1024 + kb + cs, &Al[t * 512]);
      gll16(WT + (size_t)(n0 + row) * 1024 + kb + cs, &Bl[t * 512]);
    }
    __syncthreads();
#pragma unroll
    for (int ks = 0; ks < 2; ++ks) {
      int gk = ks ? g1 : g0;                  // swizzled read granule
      s16x8 af[4], bfr[4];
#pragma unroll
      for (int i = 0; i < 4; ++i) af[i]  = *(const s16x8*)&Al[(wr + i * 16 + fr) * 64 + gk];
#pragma unroll
      for (int i = 0; i < 4; ++i) bfr[i] = *(const s16x8*)&Bl[(wc + i * 16 + fr) * 64 + gk];
#pragma unroll
      for (int mi = 0; mi < 4; ++mi)
#pragma unroll
        for (int ni = 0; ni < 4; ++ni)
          acc[mi][ni] = mfma16(af[mi], bfr[ni], acc[mi][ni]);
    }
    __syncthreads();
  }

  // epilogue: bias + RoPE + scale, LDS-bounce (per-wave 8 KB), coalesced 16B stores.
  unsigned short* W = S + wid * 4096;
  int hh = (n0l + wc) >> 6;
  int rbase = m0 + wr;
  int bn = rbase >> 8;
#pragma unroll
  for (int nf = 0; nf < 4; ++nf) {
    int d = nf * 16 + fr;
    int col = n0l + wc + d;
    float bz = bias[col];
    bool rope = (which < 2) && (nf < 2);
#pragma unroll
    for (int mf = 0; mf < 4; ++mf) {
#pragma unroll
      for (int j = 0; j < 4; ++j) {
        int row = mf * 16 + fg * 4 + j;
        int mg = rbase + row;
        float v = acc[mf][nf][j] + bz;
        if (rope) {
          float p = __shfl_xor(v, 1);
          F2 cs = tab[(mg & 4095) * 16 + (d >> 1)];
          v = (d & 1) ? fmaf(v, cs.c, p * cs.s) : fmaf(v, cs.c, -(p * cs.s));
        }
        if (which == 0) v *= 0.125f;
        W[row * 64 + (((d >> 3) ^ (row & 7)) << 3) + (d & 7)] = f2b(v);
      }
    }
  }
  asm volatile("s_waitcnt lgkmcnt(0)" ::: "memory");
  __builtin_amdgcn_sched_barrier(0);
  size_t gbase = ((size_t)(bn * 16 + hh) * 256 + (rbase & 255)) * 64;
#pragma unroll
  for (int it = 0; it < 8; ++it) {
    int r = it * 8 + (lane >> 3);
    int ch = (lane & 7) ^ (r & 7);
    s16x8 vv = *(const s16x8*)&W[r * 64 + ch * 8];
    *(s16x8*)&dst[gbase + r * 64 + (lane & 7) * 8] = vv;
  }
}

// ---------------- kernel 4: attention per (bn, h), 8 waves ------------------------------
__global__ __launch_bounds__(512, 1) void k_attn(
    const unsigned short* __restrict__ qbuf,
    const unsigned short* __restrict__ kbuf,
    const unsigned short* __restrict__ vbuf,
    unsigned short* __restrict__ xbuf) {
  __shared__ __align__(16) unsigned short Kl[256 * 64];
  __shared__ __align__(16) unsigned short Vt[64 * 264];
  __shared__ __align__(16) unsigned short Pl[8][16 * 264];
  int gb = blockIdx.x;                 // 1024 = (bn<<4)|h
  size_t base = (size_t)gb * (256 * 64);
  const unsigned short* Q = qbuf + base;
  const unsigned short* K = kbuf + base;
  const unsigned short* V = vbuf + base;
  int bn = gb >> 4, h = gb & 15;
  int tid = threadIdx.x, wid = tid >> 6, lane = tid & 63;
  int fr = lane & 15, fg = lane >> 4;

#pragma unroll
  for (int tt = 0; tt < 4; ++tt) {
    int t = wid * 4 + tt;
    int r = t * 8 + (lane >> 3);
    int csrc = (lane & 7) ^ (r & 7);
    gll16(K + r * 64 + csrc * 8, &Kl[t * 512]);
  }
  {
    int rv = tid >> 1, chalf = (tid & 1) * 32;
#pragma unroll
    for (int c8 = 0; c8 < 4; ++c8) {
      s16x8 vv = *(const s16x8*)&V[rv * 64 + chalf + c8 * 8];
#pragma unroll
      for (int j = 0; j < 8; ++j)
        Vt[(chalf + c8 * 8 + j) * 264 + rv] = (unsigned short)vv[j];
    }
  }
  __syncthreads();

  unsigned short* P = Pl[wid];
  int f7 = fr & 7;
  int c0 = (fg ^ f7) * 8;
  int c1 = ((4 + fg) ^ f7) * 8;
  for (int mtile = 0; mtile < 2; ++mtile) {
    int q0 = wid * 32 + mtile * 16;
    s16x8 qa0 = *(const s16x8*)&Q[(q0 + fr) * 64 + fg * 8];
    s16x8 qa1 = *(const s16x8*)&Q[(q0 + fr) * 64 + 32 + fg * 8];
    f32x4 sc[16] = {};
#pragma unroll
    for (int nt = 0; nt < 16; ++nt) {
      int rr = nt * 16 + fr;
      s16x8 kb0 = *(const s16x8*)&Kl[rr * 64 + c0];
      sc[nt] = mfma16(qa0, kb0, sc[nt]);
      s16x8 kb1 = *(const s16x8*)&Kl[rr * 64 + c1];
      sc[nt] = mfma16(qa1, kb1, sc[nt]);
    }
    float rs[4];
#pragma unroll
    for (int j = 0; j < 4; ++j) {
      float m = sc[0][j];
#pragma unroll
      for (int nt = 1; nt < 16; ++nt) m = fmaxf(m, sc[nt][j]);
      m = fmaxf(m, __shfl_xor(m, 1));
      m = fmaxf(m, __shfl_xor(m, 2));
      m = fmaxf(m, __shfl_xor(m, 4));
      m = fmaxf(m, __shfl_xor(m, 8));
      float sum = 0.f;
#pragma unroll
      for (int nt = 0; nt < 16; ++nt) {
        float p = __expf(sc[nt][j] - m);
        sum += p;
        P[(fg * 4 + j) * 264 + nt * 16 + fr] = f2b(p);
      }
      sum += __shfl_xor(sum, 1);
      sum += __shfl_xor(sum, 2);
      sum += __shfl_xor(sum, 4);
      sum += __shfl_xor(sum, 8);
      rs[j] = 1.0f / sum;
    }
    f32x4 o[4] = {};
#pragma unroll
    for (int ks = 0; ks < 8; ++ks) {
      s16x8 pa = *(const s16x8*)&P[fr * 264 + ks * 32 + fg * 8];
#pragma unroll
      for (int nt = 0; nt < 4; ++nt) {
        s16x8 vb = *(const s16x8*)&Vt[(nt * 16 + fr) * 264 + ks * 32 + fg * 8];
        o[nt] = mfma16(pa, vb, o[nt]);
      }
    }
#pragma unroll
    for (int nt = 0; nt < 4; ++nt)
#pragma unroll
      for (int j = 0; j < 4; ++j) {
        int srow = q0 + fg * 4 + j;
        int d = nt * 16 + fr;
        xbuf[((size_t)(bn * 256 + srow)) * 1024 + h * 64 + d] = f2b(o[nt][j] * rs[j]);
      }
  }
}

// ---------------- kernel 5: output GEMM + bo (f32) — 2-phase 128^2 + T2 -----------------
__global__ __launch_bounds__(256, 2) void k_out(
    const unsigned short* __restrict__ Xb,
    const unsigned short* __restrict__ WT,
    const float* __restrict__ bo,
    float* __restrict__ out) {
  __shared__ __align__(16) unsigned short S[16384];   // 32 KB
  unsigned short* Al = S;
  unsigned short* Bl = S + 8192;
  int bid = blockIdx.x;                       // 1024 = 128 mt x 8 nt
  int swz = (bid & 7) * 128 + (bid >> 3);     // XCD swizzle, bijective
  int mt = swz >> 3, nt = swz & 7;
  int m0 = mt * 128, n0 = nt * 128;
  int tid = threadIdx.x, wid = tid >> 6, lane = tid & 63;
  int fr = lane & 15, fg = lane >> 4, f7 = fr & 7;
  int wr = (wid >> 1) * 64, wc = (wid & 1) * 64;
  int sr = lane >> 3, scp = lane & 7;
  int g0 = (fg ^ f7) * 8, g1 = ((4 + fg) ^ f7) * 8;

  f32x4 acc[4][4] = {};
  for (int kt = 0; kt < 16; ++kt) {
    int kb = kt * 64;
#pragma unroll
    for (int tt = 0; tt < 4; ++tt) {
      int t = wid * 4 + tt;
      int row = t * 8 + sr;
      int cs = (scp ^ (row & 7)) * 8;
      gll16(Xb + (size_t)(m0 + row) * 1024 + kb + cs, &Al[t * 512]);
      gll16(WT + (size_t)(n0 + row) * 1024 + kb + cs, &Bl[t * 512]);
    }
    __syncthreads();
#pragma unroll
    for (int ks = 0; ks < 2; ++ks) {
      int gk = ks ? g1 : g0;
      s16x8 af[4], bfr[4];
#pragma unroll
      for (int i = 0; i < 4; ++i) af[i]  = *(const s16x8*)&Al[(wr + i * 16 + fr) * 64 + gk];
#pragma unroll
      for (int i = 0; i < 4; ++i) bfr[i] = *(const s16x8*)&Bl[(wc + i * 16 + fr) * 64 + gk];
#pragma unroll
      for (int mi = 0; mi < 4; ++mi)
#pragma unroll
        for (int ni = 0; ni < 4; ++ni)
          acc[mi][ni] = mfma16(af[mi], bfr[ni], acc[mi][ni]);
    }
    __syncthreads();
  }

  // f32 bounce epilogue: two 32-row passes per wave through 8 KB (2048 floats),
  // 8-float-granule swizzle (r9-verified), f32x4 coalesced stores.
  float* Wf = (float*)S + wid * 2048;
  int rbase = m0 + wr;
#pragma unroll
  for (int p = 0; p < 2; ++p) {
#pragma unroll
    for (int nf = 0; nf < 4; ++nf) {
      int d = nf * 16 + fr;
      float bz = bo[n0 + wc + d];
#pragma unroll
      for (int mh = 0; mh < 2; ++mh) {
        int mf = p * 2 + mh;
#pragma unroll
        for (int j = 0; j < 4; ++j) {
          int rloc = mh * 16 + fg * 4 + j;     // 0..31
          Wf[rloc * 64 + (((d >> 3) ^ (rloc & 7)) << 3) + (d & 7)] = acc[mf][nf][j] + bz;
        }
      }
    }
    asm volatile("s_waitcnt lgkmcnt(0)" ::: "memory");
    __builtin_amdgcn_sched_barrier(0);
#pragma unroll
    for (int it = 0; it < 8; ++it) {
      int rloc = it * 4 + (lane >> 4);         // 0..31
      int cpair = lane & 15;                   // d = cpair*4 .. +3
      int ch = (cpair >> 1) ^ (rloc & 7);
      f32x4 vv = *(const f32x4*)&Wf[rloc * 64 + ch * 8 + (cpair & 1) * 4];
      int mg = rbase + p * 32 + rloc;
      *(f32x4*)&out[(size_t)mg * 1024 + n0 + wc + cpair * 4] = vv;
    }
    asm volatile("s_waitcnt lgkmcnt(0)" ::: "memory");
    __builtin_amdgcn_sched_barrier(0);
  }
}

extern "C" void kernel_launch(void* const* d_in, const int* in_sizes, int n_in,
                              void* d_out, int out_size, void* d_ws, size_t ws_size,
                              hipStream_t stream) {
  const float* Xq  = (const float*)d_in[0];
  const float* Xkv = (const float*)d_in[1];
  const float* Wq  = (const float*)d_in[2];
  const float* bq  = (const float*)d_in[3];
  const float* Wk  = (const float*)d_in[4];
  const float* bk  = (const float*)d_in[5];
  const float* Wv  = (const float*)d_in[6];
  const float* bv  = (const float*)d_in[7];
  const float* Wo  = (const float*)d_in[8];
  const float* bo  = (const float*)d_in[9];
  float* out = (float*)d_out;

  char* ws = (char*)d_ws;
  size_t off = 0;
  F2* tab = (F2*)(ws + off);                           off += (size_t)65536 * sizeof(F2);
  unsigned short* WTqkv = (unsigned short*)(ws + off); off += (size_t)3 * 1048576 * 2;
  unsigned short* WTo   = (unsigned short*)(ws + off); off += (size_t)1048576 * 2;
  unsigned short* Xqb   = (unsigned short*)(ws + off); off += (size_t)16777216 * 2;
  unsigned short* Xkvb  = (unsigned short*)(ws + off); off += (size_t)16777216 * 2;
  unsigned short* qb = (unsigned short*)(ws + off); off += (size_t)16777216 * 2;
  unsigned short* kb = (unsigned short*)(ws + off); off += (size_t)16777216 * 2;
  unsigned short* vb = (unsigned short*)(ws + off); off += (size_t)16777216 * 2;
  unsigned short* xb = Xqb;   // alias: Xq_bf16 dead after k_qkv

  k_prep<<<8448, 256, 0, stream>>>(Xq, Xkv, Xqb, Xkvb, tab, Wq, Wk, Wv, Wo, WTqkv, WTo);
  k_qkv<<<3072, 256, 0, stream>>>(Xqb, Xkvb, WTqkv, bq, bk, bv, tab, qb, kb, vb);
  k_attn<<<1024, 512, 0, stream>>>(qb, kb, vb, xb);
  k_out<<<1024, 256, 0, stream>>>(xb, WTo, bo, out);
}